// Round 8
// baseline (170.836 us; speedup 1.0000x reference)
//
#include <hip/hip_runtime.h>
#include <hip/hip_bf16.h>

// SConv: x(8,64,128,128) f32, Coefficient(9,9), W(128,64,3,3), b(128)
// out[b,co,h,w] = sum_{c,t} z[b,c,h,w][t] * W[co,c,t] + b[co]
// z = [sorted8(y[noncenter])[0:4], center, sorted8[4:8]],
// y_i = sum_j Coefficient[i,j] * patch_j (3x3 neighborhood, zero pad 1).
//
// Round 8 (vs round 7, 100 us): LDS pipe identified as bottleneck (~60% busy:
// 294 KB/block of A-fragment re-reads, 8x redundancy over the 36 KB Z tile).
//  - Phase B concentrated in 4 waves, each 2 m-tiles x 2 n-tiles: one A-frag
//    pair feeds 4 MFMAs -> A-traffic halves to 147 KB/block. Waves 4-7 exit
//    after the barrier (they only do Phase A).
//  - SROW 580 -> 584: rows 16 B-aligned (1168 B stride, +4 banks/row rotation
//    -> <=2-way on reads = free), A-frags now single ds_read_b128.
// MFMA 16x16x32 bf16, verified layouts (m89/m91/m97). Phase A unchanged:
// f32x2 packed math, interior fast path, parity-trick packed b32 LDS stores.

#define B_   8
#define C_   64
#define H_   128
#define W_   128
#define CO_  128
#define K_   576    // C_*9
#define MT   32     // sites (w) per block
#define SROW 584    // LDS row stride in elements (1168 B, 16B-aligned rows)

typedef __attribute__((ext_vector_type(8))) short  short8;
typedef __attribute__((ext_vector_type(8))) ushort u16x8;
typedef __attribute__((ext_vector_type(8))) __bf16 bf16x8;
typedef __attribute__((ext_vector_type(4))) float  f32x4;
typedef __attribute__((ext_vector_type(2))) float  f32x2;

__device__ __forceinline__ void cswap2(f32x2 &a, f32x2 &b) {
    f32x2 lo = __builtin_elementwise_min(a, b);
    f32x2 hi = __builtin_elementwise_max(a, b);
    a = lo; b = hi;
}

__device__ __forceinline__ ushort f2bf(float f) {
    union { float f; unsigned u; } v; v.f = f;
    unsigned r = v.u + 0x7fffu + ((v.u >> 16) & 1u);  // RNE
    return (ushort)(r >> 16);
}

__device__ __forceinline__ unsigned pack2bf(float lo, float hi) {
    union { __hip_bfloat162 h; unsigned u; } cv;
    cv.h = __float22bfloat162_rn(make_float2(lo, hi));  // x->low word
    return cv.u;
}

// W[co][c][t] f32 -> bf16 (layout already B^T = [n=co][k=c*9+t])
__global__ __launch_bounds__(256) void conv_W_bf16(const float* __restrict__ Wg,
                                                   ushort* __restrict__ Wb) {
    int i = blockIdx.x * 256 + threadIdx.x;
    if (i < CO_ * K_) Wb[i] = f2bf(Wg[i]);
}

__global__ __launch_bounds__(512, 8) void sconv_mfma(
    const float* __restrict__ x,
    const float* __restrict__ Coef,
    const ushort* __restrict__ Wb,     // bf16 bits [co][k]
    const float* __restrict__ bias,
    float* __restrict__ out)
{
    __shared__ ushort Zl[MT * SROW];   // 37376 B

    const int tid = threadIdx.x;
    const int bx  = blockIdx.x;
    const int wq  = bx & 3;            // which 32-wide quarter of the row
    const int h   = (bx >> 2) & 127;
    const int b   = bx >> 9;
    const int w0  = wq * MT;

    // ---- Phase A: z for 64 c x 32 sites; 2 adjacent sites per thread ----
    #pragma unroll
    for (int it = 0; it < 2; ++it) {           // 1024 pair-tasks / 512 thr
        const int task = tid + it * 512;
        const int c  = task >> 4;
        const int pi = task & 15;              // site pair index
        const int w  = w0 + pi * 2;
        const float* xb = x + ((size_t)(b * C_ + c)) * (H_ * W_);

        // 3 rows x 4 cols of padded input (covers both sites' 3x3 patches)
        float r[3][4];
        if (h >= 1 && h <= 126 && w >= 1 && w <= 125) {
            const float* bp = xb + (h - 1) * W_ + (w - 1);
            #pragma unroll
            for (int dy = 0; dy < 3; ++dy)
                #pragma unroll
                for (int dx = 0; dx < 4; ++dx)
                    r[dy][dx] = bp[dy * W_ + dx];
        } else {
            #pragma unroll
            for (int dy = 0; dy < 3; ++dy) {
                const int hy = h + dy - 1;
                const bool hin = (unsigned)hy < (unsigned)H_;
                #pragma unroll
                for (int dx = 0; dx < 4; ++dx) {
                    const int wx = w + dx - 1;
                    const bool win = (unsigned)wx < (unsigned)W_;
                    r[dy][dx] = (hin && win) ? xb[hy * W_ + wx] : 0.0f;
                }
            }
        }

        f32x2 p2[9];
        #pragma unroll
        for (int dy = 0; dy < 3; ++dy)
            #pragma unroll
            for (int dx = 0; dx < 3; ++dx)
                p2[dy * 3 + dx] = (f32x2){ r[dy][dx], r[dy][dx + 1] };

        // y_i for i in {0,1,2,3,5,6,7,8}; Coef via uniform (scalar) loads
        f32x2 v2[8];
        #pragma unroll
        for (int ii = 0; ii < 8; ++ii) {
            const int i = ii + (ii >> 2);
            f32x2 acc = p2[0] * Coef[i * 9];
            #pragma unroll
            for (int j = 1; j < 9; ++j) acc += p2[j] * Coef[i * 9 + j];
            v2[ii] = acc;
        }

        // Batcher odd-even mergesort, 8 elems, ascending (19 comparators)
        cswap2(v2[0],v2[1]); cswap2(v2[2],v2[3]); cswap2(v2[4],v2[5]); cswap2(v2[6],v2[7]);
        cswap2(v2[0],v2[2]); cswap2(v2[1],v2[3]); cswap2(v2[4],v2[6]); cswap2(v2[5],v2[7]);
        cswap2(v2[1],v2[2]); cswap2(v2[5],v2[6]);
        cswap2(v2[0],v2[4]); cswap2(v2[1],v2[5]); cswap2(v2[2],v2[6]); cswap2(v2[3],v2[7]);
        cswap2(v2[2],v2[4]); cswap2(v2[3],v2[5]);
        cswap2(v2[1],v2[2]); cswap2(v2[3],v2[4]); cswap2(v2[5],v2[6]);

        f32x2 z2[9] = { v2[0], v2[1], v2[2], v2[3], p2[4],
                        v2[4], v2[5], v2[6], v2[7] };

        const int k0 = c * 9;
        ushort* zr0 = &Zl[(pi * 2    ) * SROW];
        ushort* zr1 = &Zl[(pi * 2 + 1) * SROW];
        if ((k0 & 1) == 0) {                    // pairs k0.., single at k0+8
            #pragma unroll
            for (int q = 0; q < 4; ++q) {
                *(unsigned*)&zr0[k0 + 2*q] = pack2bf(z2[2*q][0], z2[2*q+1][0]);
                *(unsigned*)&zr1[k0 + 2*q] = pack2bf(z2[2*q][1], z2[2*q+1][1]);
            }
            zr0[k0 + 8] = f2bf(z2[8][0]);
            zr1[k0 + 8] = f2bf(z2[8][1]);
        } else {                                // single at k0, pairs k0+1..
            zr0[k0] = f2bf(z2[0][0]);
            zr1[k0] = f2bf(z2[0][1]);
            #pragma unroll
            for (int q = 0; q < 4; ++q) {
                *(unsigned*)&zr0[k0 + 1 + 2*q] = pack2bf(z2[1+2*q][0], z2[2+2*q][0]);
                *(unsigned*)&zr1[k0 + 1 + 2*q] = pack2bf(z2[1+2*q][1], z2[2+2*q][1]);
            }
        }
    }
    __syncthreads();

    // ---- Phase B: 4 GEMM waves, each 2 m-tiles x 2 n-tiles (A reused) ----
    const int wave = tid >> 6;
    if (wave >= 4) return;             // waves 4-7: Phase A only

    const int lane = tid & 63;
    const int quad = lane >> 4;
    const int l16  = lane & 15;
    const int nt0  = wave * 2;         // n-tiles nt0, nt0+1 (co)

    const ushort* arow0 = &Zl[l16 * SROW];           // m-tile 0 row
    const ushort* arow1 = &Zl[(l16 + 16) * SROW];    // m-tile 1 row
    const ushort* brow0 = Wb + (size_t)(nt0 * 16 + l16) * K_ + quad * 8;
    const ushort* brow1 = brow0 + (size_t)16 * K_;

    f32x4 acc00 = {0.f,0.f,0.f,0.f}, acc01 = acc00, acc10 = acc00, acc11 = acc00;

    #pragma unroll
    for (int ks = 0; ks < 18; ++ks) {
        const int ko = ks * 32 + quad * 8;     // this lane's k-chunk base
        bf16x8 a0  = __builtin_bit_cast(bf16x8, *(const u16x8*)(arow0 + ko));
        bf16x8 a1  = __builtin_bit_cast(bf16x8, *(const u16x8*)(arow1 + ko));
        bf16x8 bb0 = __builtin_bit_cast(bf16x8, *(const short8*)(brow0 + ks * 32));
        bf16x8 bb1 = __builtin_bit_cast(bf16x8, *(const short8*)(brow1 + ks * 32));
        acc00 = __builtin_amdgcn_mfma_f32_16x16x32_bf16(a0, bb0, acc00, 0, 0, 0);
        acc10 = __builtin_amdgcn_mfma_f32_16x16x32_bf16(a1, bb0, acc10, 0, 0, 0);
        acc01 = __builtin_amdgcn_mfma_f32_16x16x32_bf16(a0, bb1, acc01, 0, 0, 0);
        acc11 = __builtin_amdgcn_mfma_f32_16x16x32_bf16(a1, bb1, acc11, 0, 0, 0);
    }

    // ---- Epilogue: C/D row=(quad*4+reg) -> w, col=l16 -> co-local ----
    #pragma unroll
    for (int j = 0; j < 2; ++j) {
        const int co = (nt0 + j) * 16 + l16;
        const float bv = bias[co];
        float* orow = out + (((size_t)(b * CO_ + co)) * H_ + h) * W_ + w0;
        const f32x4 r0 = j ? acc01 : acc00;
        const f32x4 r1 = j ? acc11 : acc10;
        const int wl0 = quad * 4;
        *(float4*)(orow + wl0)      = make_float4(r0.x + bv, r0.y + bv, r0.z + bv, r0.w + bv);
        *(float4*)(orow + wl0 + 16) = make_float4(r1.x + bv, r1.y + bv, r1.z + bv, r1.w + bv);
    }
}

// ---- fp32 fallback (round-1 kernel, direct W layout) if ws is too small ----
#define WT 16
__device__ __forceinline__ void cswap(float &a, float &b) {
    float lo = fminf(a, b);
    float hi = fmaxf(a, b);
    a = lo; b = hi;
}
__global__ __launch_bounds__(256) void sconv_fp32(
    const float* __restrict__ x, const float* __restrict__ Coef,
    const float* __restrict__ Wg, const float* __restrict__ bias,
    float* __restrict__ out)
{
    __shared__ float Cf[81];
    __shared__ float Zl[C_ * 9 * WT];
    const int tid = threadIdx.x;
    const int bx  = blockIdx.x;
    const int wt  = bx & 7;
    const int h   = (bx >> 3) & 127;
    const int b   = bx >> 10;
    const int w0  = wt * WT;
    if (tid < 81) Cf[tid] = Coef[tid];
    __syncthreads();
    for (int task = tid; task < C_ * WT; task += 256) {
        const int c = task >> 4, wl = task & 15, w = w0 + wl;
        const float* xb = x + (b * C_ + c) * H_ * W_;
        float p[9];
        #pragma unroll
        for (int dy = 0; dy < 3; ++dy) {
            const int hy = h + dy - 1; const bool hin = (unsigned)hy < (unsigned)H_;
            #pragma unroll
            for (int dx = 0; dx < 3; ++dx) {
                const int wx = w + dx - 1; const bool win = (unsigned)wx < (unsigned)W_;
                p[dy * 3 + dx] = (hin && win) ? xb[hy * W_ + wx] : 0.0f;
            }
        }
        float v[8];
        #pragma unroll
        for (int ii = 0; ii < 8; ++ii) {
            const int i = ii + (ii >> 2);
            float acc = 0.0f;
            #pragma unroll
            for (int j = 0; j < 9; ++j) acc = fmaf(Cf[i * 9 + j], p[j], acc);
            v[ii] = acc;
        }
        cswap(v[0], v[1]); cswap(v[2], v[3]); cswap(v[4], v[5]); cswap(v[6], v[7]);
        cswap(v[0], v[2]); cswap(v[1], v[3]); cswap(v[4], v[6]); cswap(v[5], v[7]);
        cswap(v[1], v[2]); cswap(v[5], v[6]);
        cswap(v[0], v[4]); cswap(v[1], v[5]); cswap(v[2], v[6]); cswap(v[3], v[7]);
        cswap(v[2], v[4]); cswap(v[3], v[5]);
        cswap(v[1], v[2]); cswap(v[3], v[4]); cswap(v[5], v[6]);
        const int base = c * 9 * WT + wl;
        Zl[base + 0*WT]=v[0]; Zl[base + 1*WT]=v[1]; Zl[base + 2*WT]=v[2]; Zl[base + 3*WT]=v[3];
        Zl[base + 4*WT]=p[4];
        Zl[base + 5*WT]=v[4]; Zl[base + 6*WT]=v[5]; Zl[base + 7*WT]=v[6]; Zl[base + 8*WT]=v[7];
    }
    __syncthreads();
    const int co = tid >> 1, w0l = (tid & 1) * 8;
    float acc[8];
    #pragma unroll
    for (int i = 0; i < 8; ++i) acc[i] = 0.0f;
    for (int c = 0; c < C_; ++c) {
        #pragma unroll
        for (int t = 0; t < 9; ++t) {
            const float wv = Wg[(co * C_ + c) * 9 + t];
            const float* zp = &Zl[(c * 9 + t) * WT + w0l];
            const float4 za = *(const float4*)zp;
            const float4 zb = *(const float4*)(zp + 4);
            acc[0]=fmaf(za.x,wv,acc[0]); acc[1]=fmaf(za.y,wv,acc[1]);
            acc[2]=fmaf(za.z,wv,acc[2]); acc[3]=fmaf(za.w,wv,acc[3]);
            acc[4]=fmaf(zb.x,wv,acc[4]); acc[5]=fmaf(zb.y,wv,acc[5]);
            acc[6]=fmaf(zb.z,wv,acc[6]); acc[7]=fmaf(zb.w,wv,acc[7]);
        }
    }
    const float bv = bias[co];
    float* op = out + ((b * CO_ + co) * H_ + h) * W_ + w0 + w0l;
    *(float4*)(op)     = make_float4(acc[0]+bv, acc[1]+bv, acc[2]+bv, acc[3]+bv);
    *(float4*)(op + 4) = make_float4(acc[4]+bv, acc[5]+bv, acc[6]+bv, acc[7]+bv);
}

extern "C" void kernel_launch(void* const* d_in, const int* in_sizes, int n_in,
                              void* d_out, int out_size, void* d_ws, size_t ws_size,
                              hipStream_t stream) {
    const float* x    = (const float*)d_in[0];
    const float* Coef = (const float*)d_in[1];
    const float* Wg   = (const float*)d_in[2];
    const float* bias = (const float*)d_in[3];
    float* out = (float*)d_out;

    const size_t need = (size_t)CO_ * K_ * sizeof(ushort);   // 147456 B
    if (ws_size >= need) {
        ushort* Wb = (ushort*)d_ws;
        conv_W_bf16<<<(CO_ * K_ + 255) / 256, 256, 0, stream>>>(Wg, Wb);
        sconv_mfma<<<B_ * H_ * 4, 512, 0, stream>>>(x, Coef, Wb, bias, out);
    } else {
        sconv_fp32<<<B_ * H_ * 8, 256, 0, stream>>>(x, Coef, Wg, bias, out);
    }
}